// Round 1
// baseline (534.957 us; speedup 1.0000x reference)
//
#include <hip/hip_runtime.h>
#include <math.h>

#define NT 16384
#define DM 2048
#define NE 64
#define TOPK 8
#define LTAX 0.04f
#define HYST 0.1f
#define ALPHA 0.7f

typedef unsigned int u32;

__device__ __forceinline__ float warp8_sum(float v) {
  v += __shfl_xor(v, 1);
  v += __shfl_xor(v, 2);
  v += __shfl_xor(v, 4);
  return v;
}
__device__ __forceinline__ float warp8_max(float v) {
  v = fmaxf(v, __shfl_xor(v, 1));
  v = fmaxf(v, __shfl_xor(v, 2));
  v = fmaxf(v, __shfl_xor(v, 4));
  return v;
}

// ---------------- K0: detect prev_mask storage format ----------------
// bool input may arrive as u8 (raw numpy bool), i32, or f32. With exactly
// 8/64 true per row, nonzero-byte counts over the first NT*NE bytes are:
// u8: 131072, f32: 65536, i32: 32768 -> cleanly separable.
__global__ void k_detect(const uint4* __restrict__ pm, int* __restrict__ flag) {
  __shared__ int red[256];
  const int tid = threadIdx.x;
  int c = 0;
  const int n16 = NT * NE / 16;
  for (int i = tid; i < n16; i += 256) {
    uint4 v = pm[i];
    u32 w;
    w = v.x; c += ((w & 0xffu) != 0) + ((w & 0xff00u) != 0) + ((w & 0xff0000u) != 0) + ((w & 0xff000000u) != 0);
    w = v.y; c += ((w & 0xffu) != 0) + ((w & 0xff00u) != 0) + ((w & 0xff0000u) != 0) + ((w & 0xff000000u) != 0);
    w = v.z; c += ((w & 0xffu) != 0) + ((w & 0xff00u) != 0) + ((w & 0xff0000u) != 0) + ((w & 0xff000000u) != 0);
    w = v.w; c += ((w & 0xffu) != 0) + ((w & 0xff00u) != 0) + ((w & 0xff0000u) != 0) + ((w & 0xff000000u) != 0);
  }
  red[tid] = c;
  __syncthreads();
  for (int s = 128; s; s >>= 1) {
    if (tid < s) red[tid] += red[tid + s];
    __syncthreads();
  }
  if (tid == 0) {
    int n = red[0];
    *flag = (n > 98304) ? 0 : ((n > 49152) ? 2 : 1);   // 0=u8, 2=f32, 1=i32
  }
}

// ---------------- K1: logits = x@W^T + b, center, softmax ----------------
// 64 tokens/block, 256 threads. Thread (eg=tid&7, tg=tid>>3) owns 2 tokens
// (tg*2+i) x 8 experts (eg+8j, strided so ws reads are bank-conflict-free).
// xs: [64][64] with float4-column XOR swizzle by (row>>1)&7 (conflict-free
// reads; r>>1 == tg for the reader). ws: stride 68 floats (4*e mod 32 spread).
__launch_bounds__(256)
__global__ void k_gemm(const float* __restrict__ x, const float* __restrict__ W,
                       const float* __restrict__ b,
                       float* __restrict__ Lg, float* __restrict__ Mg) {
  __shared__ float xs[64 * 64];
  __shared__ float ws[64 * 68];
  const int tid = threadIdx.x;
  const int eg = tid & 7;
  const int tg = tid >> 3;               // 0..31
  const int row0 = blockIdx.x * 64;

  float acc[2][8];
#pragma unroll
  for (int i = 0; i < 2; i++)
#pragma unroll
    for (int j = 0; j < 8; j++) acc[i][j] = 0.f;

  for (int kc = 0; kc < DM; kc += 64) {
#pragma unroll
    for (int i = 0; i < 4; i++) {
      int idx = tid + i * 256;           // float4 index 0..1023
      int r = idx >> 4;
      int c4 = idx & 15;
      float4 v = *(const float4*)(x + (size_t)(row0 + r) * DM + kc + c4 * 4);
      int sc = c4 ^ ((r >> 1) & 7);
      *(float4*)(xs + r * 64 + sc * 4) = v;
    }
#pragma unroll
    for (int i = 0; i < 4; i++) {
      int idx = tid + i * 256;
      int e = idx >> 4;
      int c4 = idx & 15;
      float4 v = *(const float4*)(W + (size_t)e * DM + kc + c4 * 4);
      *(float4*)(ws + e * 68 + c4 * 4) = v;
    }
    __syncthreads();
#pragma unroll
    for (int k4 = 0; k4 < 16; k4++) {
      float4 xv[2];
#pragma unroll
      for (int i = 0; i < 2; i++) {
        int r = tg * 2 + i;
        xv[i] = *(const float4*)(xs + r * 64 + ((k4 ^ (tg & 7)) * 4));
      }
      float4 wv[8];
#pragma unroll
      for (int j = 0; j < 8; j++) {
        int e = eg + 8 * j;
        wv[j] = *(const float4*)(ws + e * 68 + k4 * 4);
      }
#pragma unroll
      for (int i = 0; i < 2; i++)
#pragma unroll
        for (int j = 0; j < 8; j++) {
          acc[i][j] = fmaf(xv[i].x, wv[j].x, acc[i][j]);
          acc[i][j] = fmaf(xv[i].y, wv[j].y, acc[i][j]);
          acc[i][j] = fmaf(xv[i].z, wv[j].z, acc[i][j]);
          acc[i][j] = fmaf(xv[i].w, wv[j].w, acc[i][j]);
        }
    }
    __syncthreads();
  }

  float bias[8];
#pragma unroll
  for (int j = 0; j < 8; j++) bias[j] = b[eg + 8 * j];

#pragma unroll
  for (int i = 0; i < 2; i++) {
    const int row = row0 + tg * 2 + i;
    float l[8];
    float s = 0.f;
#pragma unroll
    for (int j = 0; j < 8; j++) { l[j] = acc[i][j] + bias[j]; s += l[j]; }
    s = warp8_sum(s);
    const float mean = s * (1.0f / 64.0f);
    float mx = -1e30f;
#pragma unroll
    for (int j = 0; j < 8; j++) { l[j] -= mean; mx = fmaxf(mx, l[j]); }
    mx = warp8_max(mx);
    float p[8], ps = 0.f;
#pragma unroll
    for (int j = 0; j < 8; j++) { p[j] = expf(l[j] - mx); ps += p[j]; }
    ps = warp8_sum(ps);
    const float inv = 1.0f / ps;
    float* Lr = Lg + (size_t)row * NE;
    float* Mr = Mg + (size_t)row * NE;
#pragma unroll
    for (int j = 0; j < 8; j++) {
      Lr[eg + 8 * j] = l[j];
      Mr[eg + 8 * j] = p[j] * inv;
    }
  }
}

// ---------------- K2: Gram partials: Cpart[b] = sum_t M[t]^T M[t] ----------------
__launch_bounds__(256)
__global__ void k_gram(const float* __restrict__ Mg, float* __restrict__ Cpart) {
  __shared__ float ms[16 * 68];
  const int tid = threadIdx.x;
  const int i0 = (tid >> 4) * 4;
  const int j0 = (tid & 15) * 4;
  const int t0 = blockIdx.x * 256;
  float acc[4][4];
#pragma unroll
  for (int a = 0; a < 4; a++)
#pragma unroll
    for (int c = 0; c < 4; c++) acc[a][c] = 0.f;

  for (int ch = 0; ch < 256; ch += 16) {
    {
      int r = tid >> 4, c4 = tid & 15;
      float4 v = *(const float4*)(Mg + (size_t)(t0 + ch + r) * NE + c4 * 4);
      *(float4*)(ms + r * 68 + c4 * 4) = v;
    }
    __syncthreads();
#pragma unroll
    for (int t = 0; t < 16; t++) {
      float4 a = *(const float4*)(ms + t * 68 + i0);
      float4 bb = *(const float4*)(ms + t * 68 + j0);
      acc[0][0] = fmaf(a.x, bb.x, acc[0][0]); acc[0][1] = fmaf(a.x, bb.y, acc[0][1]);
      acc[0][2] = fmaf(a.x, bb.z, acc[0][2]); acc[0][3] = fmaf(a.x, bb.w, acc[0][3]);
      acc[1][0] = fmaf(a.y, bb.x, acc[1][0]); acc[1][1] = fmaf(a.y, bb.y, acc[1][1]);
      acc[1][2] = fmaf(a.y, bb.z, acc[1][2]); acc[1][3] = fmaf(a.y, bb.w, acc[1][3]);
      acc[2][0] = fmaf(a.z, bb.x, acc[2][0]); acc[2][1] = fmaf(a.z, bb.y, acc[2][1]);
      acc[2][2] = fmaf(a.z, bb.z, acc[2][2]); acc[2][3] = fmaf(a.z, bb.w, acc[2][3]);
      acc[3][0] = fmaf(a.w, bb.x, acc[3][0]); acc[3][1] = fmaf(a.w, bb.y, acc[3][1]);
      acc[3][2] = fmaf(a.w, bb.z, acc[3][2]); acc[3][3] = fmaf(a.w, bb.w, acc[3][3]);
    }
    __syncthreads();
  }
  float* outp = Cpart + (size_t)blockIdx.x * 4096;
#pragma unroll
  for (int ii = 0; ii < 4; ii++) {
    float4 v = make_float4(acc[ii][0], acc[ii][1], acc[ii][2], acc[ii][3]);
    *(float4*)(outp + (i0 + ii) * 64 + j0) = v;
  }
}

// ---------------- K3: reduce Gram partials, zero diagonal ----------------
__global__ void k_gram_red(const float* __restrict__ Cpart, float* __restrict__ C) {
  const int idx = blockIdx.x * 256 + threadIdx.x;   // 0..4095
  float s = 0.f;
  for (int bb = 0; bb < 64; bb++) s += Cpart[bb * 4096 + idx];
  const int i = idx >> 6, j = idx & 63;
  C[idx] = (i == j) ? 0.f : s;
}

// ---------------- K4: correlation-tax correction + 2nd softmax ----------------
__launch_bounds__(256)
__global__ void k_correct(const float* __restrict__ Lg, float* __restrict__ Mg,
                          const float* __restrict__ C) {
  __shared__ float Cs[4096];
  __shared__ float ms[32 * 65];
  const int tid = threadIdx.x;
  const int eg = tid & 7, tg = tid >> 3;
  const int row = blockIdx.x * 32 + tg;
#pragma unroll
  for (int i = 0; i < 4; i++) {
    int idx = tid + i * 256;
    *(float4*)(Cs + idx * 4) = *(const float4*)(C + idx * 4);
  }
  float m[8];
  {
    float4 a = *(const float4*)(Mg + (size_t)row * NE + eg * 8);
    float4 bb = *(const float4*)(Mg + (size_t)row * NE + eg * 8 + 4);
    m[0] = a.x; m[1] = a.y; m[2] = a.z; m[3] = a.w;
    m[4] = bb.x; m[5] = bb.y; m[6] = bb.z; m[7] = bb.w;
  }
#pragma unroll
  for (int j = 0; j < 8; j++) ms[tg * 65 + eg * 8 + j] = m[j];
  __syncthreads();
  float g[8];
#pragma unroll
  for (int j = 0; j < 8; j++) g[j] = 0.f;
  for (int f = 0; f < 64; f++) {
    float mf = ms[tg * 65 + f];
    float4 c0 = *(const float4*)(Cs + f * 64 + eg * 8);
    float4 c1 = *(const float4*)(Cs + f * 64 + eg * 8 + 4);
    g[0] = fmaf(mf, c0.x, g[0]); g[1] = fmaf(mf, c0.y, g[1]);
    g[2] = fmaf(mf, c0.z, g[2]); g[3] = fmaf(mf, c0.w, g[3]);
    g[4] = fmaf(mf, c1.x, g[4]); g[5] = fmaf(mf, c1.y, g[5]);
    g[6] = fmaf(mf, c1.z, g[6]); g[7] = fmaf(mf, c1.w, g[7]);
  }
  float dot = 0.f;
#pragma unroll
  for (int j = 0; j < 8; j++) dot += m[j] * (4.f * g[j]);
  dot = warp8_sum(dot);
  float l2[8];
  {
    float4 a = *(const float4*)(Lg + (size_t)row * NE + eg * 8);
    float4 bb = *(const float4*)(Lg + (size_t)row * NE + eg * 8 + 4);
    float ll[8] = {a.x, a.y, a.z, a.w, bb.x, bb.y, bb.z, bb.w};
#pragma unroll
    for (int j = 0; j < 8; j++)
      l2[j] = ll[j] - LTAX * (m[j] * (4.f * g[j] - dot));
  }
  float mx = -1e30f;
#pragma unroll
  for (int j = 0; j < 8; j++) mx = fmaxf(mx, l2[j]);
  mx = warp8_max(mx);
  float p[8], ps = 0.f;
#pragma unroll
  for (int j = 0; j < 8; j++) { p[j] = expf(l2[j] - mx); ps += p[j]; }
  ps = warp8_sum(ps);
  const float inv = 1.0f / ps;
  float4 o0 = make_float4(p[0] * inv, p[1] * inv, p[2] * inv, p[3] * inv);
  float4 o1 = make_float4(p[4] * inv, p[5] * inv, p[6] * inv, p[7] * inv);
  *(float4*)(Mg + (size_t)row * NE + eg * 8) = o0;
  *(float4*)(Mg + (size_t)row * NE + eg * 8 + 4) = o1;
}

// ---------------- K5: Sinkhorn column-sum partials ----------------
__global__ void k_colsum(const float* __restrict__ Mg, float* __restrict__ colpart) {
  __shared__ float red[256];
  const int tid = threadIdx.x;
  const int e = tid & 63, q = tid >> 6;
  const int t0 = blockIdx.x * 64;
  float s = 0.f;
  for (int t = q; t < 64; t += 4) s += Mg[(size_t)(t0 + t) * NE + e];
  red[tid] = s;
  __syncthreads();
  if (tid < 64)
    colpart[blockIdx.x * 64 + tid] = red[tid] + red[tid + 64] + red[tid + 128] + red[tid + 192];
}

// ---------------- K6: Sinkhorn column scale + row normalize ----------------
__global__ void k_colrow(float* __restrict__ Mg, const float* __restrict__ colpart) {
  __shared__ float red[256];
  __shared__ float fac[64];
  const int tid = threadIdx.x;
  {
    const int e = tid & 63, q = tid >> 6;
    float s = 0.f;
    for (int bb = q; bb < 256; bb += 4) s += colpart[bb * 64 + e];
    red[tid] = s;
  }
  __syncthreads();
  if (tid < 64) {
    float s = red[tid] + red[tid + 64] + red[tid + 128] + red[tid + 192];
    fac[tid] = (1.0f / 256.0f) / fmaxf(s, 1e-12f);   // (E/n)/clip(colsum)
  }
  __syncthreads();
  const int eg = tid & 7, tg = tid >> 3;
  float f0[8];
#pragma unroll
  for (int j = 0; j < 8; j++) f0[j] = fac[eg * 8 + j];
#pragma unroll
  for (int it = 0; it < 2; it++) {
    const int row = blockIdx.x * 64 + it * 32 + tg;
    float* Mr = Mg + (size_t)row * NE + eg * 8;
    float4 a = *(const float4*)(Mr);
    float4 bb = *(const float4*)(Mr + 4);
    float v[8] = {a.x * f0[0], a.y * f0[1], a.z * f0[2], a.w * f0[3],
                  bb.x * f0[4], bb.y * f0[5], bb.z * f0[6], bb.w * f0[7]};
    float rs = 0.f;
#pragma unroll
    for (int j = 0; j < 8; j++) rs += v[j];
    rs = warp8_sum(rs);
    const float inv = 1.0f / fmaxf(rs, 1e-12f);
    float4 o0 = make_float4(v[0] * inv, v[1] * inv, v[2] * inv, v[3] * inv);
    float4 o1 = make_float4(v[4] * inv, v[5] * inv, v[6] * inv, v[7] * inv);
    *(float4*)(Mr) = o0;
    *(float4*)(Mr + 4) = o1;
  }
}

// ---------------- K7: damping + hysteresis + normalize + top-k ----------------
__launch_bounds__(256)
__global__ void k_final(const float* __restrict__ Mg, const float* __restrict__ pp,
                        const void* __restrict__ pmask, const int* __restrict__ flagp,
                        float* __restrict__ out) {
  const int tid = threadIdx.x;
  const int eg = tid & 7, tg = tid >> 3;
  const int flag = *flagp;
  float* mout = out;
  float* kout = out + (size_t)NT * NE;
#pragma unroll
  for (int it = 0; it < 2; it++) {
    const int row = blockIdx.x * 64 + it * 32 + tg;
    const float* Mr = Mg + (size_t)row * NE + eg * 8;
    const float* Pr = pp + (size_t)row * NE + eg * 8;
    float4 a = *(const float4*)Mr, b2 = *(const float4*)(Mr + 4);
    float4 c = *(const float4*)Pr, d = *(const float4*)(Pr + 4);
    float mv[8] = {a.x, a.y, a.z, a.w, b2.x, b2.y, b2.z, b2.w};
    float pv[8] = {c.x, c.y, c.z, c.w, d.x, d.y, d.z, d.w};
    float mk[8];
    if (flag == 0) {                 // u8 bytes
      const u32* pb = (const u32*)pmask + row * 16 + eg * 2;
      u32 w0 = pb[0], w1 = pb[1];
#pragma unroll
      for (int j = 0; j < 4; j++) mk[j] = ((w0 >> (8 * j)) & 0xffu) ? 1.f : 0.f;
#pragma unroll
      for (int j = 0; j < 4; j++) mk[4 + j] = ((w1 >> (8 * j)) & 0xffu) ? 1.f : 0.f;
    } else if (flag == 1) {          // int32
      const int* pb = (const int*)pmask + (size_t)row * NE + eg * 8;
#pragma unroll
      for (int j = 0; j < 8; j++) mk[j] = pb[j] ? 1.f : 0.f;
    } else {                         // float32
      const float* pb = (const float*)pmask + (size_t)row * NE + eg * 8;
#pragma unroll
      for (int j = 0; j < 8; j++) mk[j] = (pb[j] != 0.f) ? 1.f : 0.f;
    }
    float msum = 0.f;
#pragma unroll
    for (int j = 0; j < 8; j++) msum += mk[j];
    msum = warp8_sum(msum);
    const float hscale = HYST / fmaxf(msum, 1.0f);
    float v[8];
    float s = 0.f;
#pragma unroll
    for (int j = 0; j < 8; j++) {
      float base = (1.f - ALPHA) * pv[j] + ALPHA * mv[j];
      v[j] = (1.f - HYST) * base + hscale * mk[j];
      s += v[j];
    }
    s = warp8_sum(s);
    const float inv = 1.0f / fmaxf(s, 1e-12f);
#pragma unroll
    for (int j = 0; j < 8; j++) v[j] *= inv;
    {
      float4 o0 = make_float4(v[0], v[1], v[2], v[3]);
      float4 o1 = make_float4(v[4], v[5], v[6], v[7]);
      *(float4*)(mout + (size_t)row * NE + eg * 8) = o0;
      *(float4*)(mout + (size_t)row * NE + eg * 8 + 4) = o1;
    }
    // top-8: expert e selected iff #{f beats e} < 8; beats = greater, or
    // equal with lower index (matches stable descending top_k).
    int cnt[8];
#pragma unroll
    for (int j = 0; j < 8; j++) cnt[j] = 0;
    const int gb = (tid & 63) & ~7;
#pragma unroll
    for (int s8 = 0; s8 < 8; s8++) {
#pragma unroll
      for (int jo = 0; jo < 8; jo++) {
        float o = __shfl(v[jo], gb + s8, 64);
        int oe = s8 * 8 + jo;
#pragma unroll
        for (int j2 = 0; j2 < 8; j2++) {
          int me = eg * 8 + j2;
          if (o > v[j2] || (o == v[j2] && oe < me)) cnt[j2]++;
        }
      }
    }
    float4 k0 = make_float4(cnt[0] < TOPK ? 1.f : 0.f, cnt[1] < TOPK ? 1.f : 0.f,
                            cnt[2] < TOPK ? 1.f : 0.f, cnt[3] < TOPK ? 1.f : 0.f);
    float4 k1 = make_float4(cnt[4] < TOPK ? 1.f : 0.f, cnt[5] < TOPK ? 1.f : 0.f,
                            cnt[6] < TOPK ? 1.f : 0.f, cnt[7] < TOPK ? 1.f : 0.f);
    *(float4*)(kout + (size_t)row * NE + eg * 8) = k0;
    *(float4*)(kout + (size_t)row * NE + eg * 8 + 4) = k1;
  }
}

extern "C" void kernel_launch(void* const* d_in, const int* in_sizes, int n_in,
                              void* d_out, int out_size, void* d_ws, size_t ws_size,
                              hipStream_t stream) {
  const float* x = (const float*)d_in[0];
  const float* W = (const float*)d_in[1];
  const float* b = (const float*)d_in[2];
  const float* pp = (const float*)d_in[3];
  const void* pmask = d_in[4];
  float* out = (float*)d_out;

  float* wsf = (float*)d_ws;
  float* Mbuf = wsf;                                  // NT*NE
  float* Lbuf = wsf + (size_t)NT * NE;                // NT*NE
  float* Cpart = Lbuf + (size_t)NT * NE;              // 64*4096
  float* Cm = Cpart + 64 * 4096;                      // 4096
  float* colpart = Cm + 4096;                         // 256*64
  int* flag = (int*)(colpart + 256 * 64);

  k_detect<<<1, 256, 0, stream>>>((const uint4*)pmask, flag);
  k_gemm<<<256, 256, 0, stream>>>(x, W, b, Lbuf, Mbuf);
  k_gram<<<64, 256, 0, stream>>>(Mbuf, Cpart);
  k_gram_red<<<16, 256, 0, stream>>>(Cpart, Cm);
  k_correct<<<512, 256, 0, stream>>>(Lbuf, Mbuf, Cm);
  for (int i = 0; i < 10; i++) {
    k_colsum<<<256, 256, 0, stream>>>(Mbuf, colpart);
    k_colrow<<<256, 256, 0, stream>>>(Mbuf, colpart);
  }
  k_final<<<256, 256, 0, stream>>>(Mbuf, pp, pmask, flag, out);
}

// Round 3
// 378.638 us; speedup vs baseline: 1.4128x; 1.4128x over previous
//
#include <hip/hip_runtime.h>
#include <math.h>

#define NT 16384
#define DM 2048
#define NE 64
#define TOPK 8
#define LTAX 0.04f
#define HYST 0.1f
#define ALPHA 0.7f

typedef unsigned int u32;

__device__ __forceinline__ float warp8_sum(float v) {
  v += __shfl_xor(v, 1);
  v += __shfl_xor(v, 2);
  v += __shfl_xor(v, 4);
  return v;
}
__device__ __forceinline__ float warp8_max(float v) {
  v = fmaxf(v, __shfl_xor(v, 1));
  v = fmaxf(v, __shfl_xor(v, 2));
  v = fmaxf(v, __shfl_xor(v, 4));
  return v;
}
__device__ __forceinline__ float warp4_sum(float v) {
  v += __shfl_xor(v, 1);
  v += __shfl_xor(v, 2);
  return v;
}
__device__ __forceinline__ float warp4_max(float v) {
  v = fmaxf(v, __shfl_xor(v, 1));
  v = fmaxf(v, __shfl_xor(v, 2));
  return v;
}

// ---------------- K0: detect prev_mask storage format (64KB sample) --------
// u8 -> 8192 nonzero bytes, f32 -> 4096, i32 -> 2048 in first 64KB.
__global__ void k_detect(const uint4* __restrict__ pm, int* __restrict__ flag) {
  __shared__ int red[256];
  const int tid = threadIdx.x;
  int c = 0;
  const int n16 = 65536 / 16;
  for (int i = tid; i < n16; i += 256) {
    uint4 v = pm[i];
    u32 w;
    w = v.x; c += ((w & 0xffu) != 0) + ((w & 0xff00u) != 0) + ((w & 0xff0000u) != 0) + ((w & 0xff000000u) != 0);
    w = v.y; c += ((w & 0xffu) != 0) + ((w & 0xff00u) != 0) + ((w & 0xff0000u) != 0) + ((w & 0xff000000u) != 0);
    w = v.z; c += ((w & 0xffu) != 0) + ((w & 0xff00u) != 0) + ((w & 0xff0000u) != 0) + ((w & 0xff000000u) != 0);
    w = v.w; c += ((w & 0xffu) != 0) + ((w & 0xff00u) != 0) + ((w & 0xff0000u) != 0) + ((w & 0xff000000u) != 0);
  }
  red[tid] = c;
  __syncthreads();
  for (int s = 128; s; s >>= 1) {
    if (tid < s) red[tid] += red[tid + s];
    __syncthreads();
  }
  if (tid == 0) {
    int n = red[0];
    *flag = (n > 6144) ? 0 : ((n > 3072) ? 2 : 1);   // 0=u8, 2=f32, 1=i32
  }
}

// ---------------- K1: split-K GEMM partials -> plain stores (deterministic) -
// blockIdx = tb*SPLITK + ks. Lpart[ks][row][e] = sum over K slice.
__launch_bounds__(256)
__global__ void k_gemm(const float* __restrict__ x, const float* __restrict__ W,
                       float* __restrict__ Lpart, int lg) {
  __shared__ float xs[64 * 64];
  __shared__ float ws[64 * 68];
  const int tid = threadIdx.x;
  const int eg = tid & 7;
  const int tg = tid >> 3;               // 0..31
  const int row0 = (blockIdx.x >> lg) * 64;
  const int ks = blockIdx.x & ((1 << lg) - 1);
  const int klen = DM >> lg;
  const int k0 = ks * klen;

  float acc[2][8];
#pragma unroll
  for (int i = 0; i < 2; i++)
#pragma unroll
    for (int j = 0; j < 8; j++) acc[i][j] = 0.f;

  for (int kc = k0; kc < k0 + klen; kc += 64) {
#pragma unroll
    for (int i = 0; i < 4; i++) {
      int idx = tid + i * 256;           // float4 index 0..1023
      int r = idx >> 4;
      int c4 = idx & 15;
      float4 v = *(const float4*)(x + (size_t)(row0 + r) * DM + kc + c4 * 4);
      int sc = c4 ^ ((r >> 1) & 7);
      *(float4*)(xs + r * 64 + sc * 4) = v;
    }
#pragma unroll
    for (int i = 0; i < 4; i++) {
      int idx = tid + i * 256;
      int e = idx >> 4;
      int c4 = idx & 15;
      float4 v = *(const float4*)(W + (size_t)e * DM + kc + c4 * 4);
      *(float4*)(ws + e * 68 + c4 * 4) = v;
    }
    __syncthreads();
#pragma unroll
    for (int k4 = 0; k4 < 16; k4++) {
      float4 xv[2];
#pragma unroll
      for (int i = 0; i < 2; i++) {
        int r = tg * 2 + i;
        xv[i] = *(const float4*)(xs + r * 64 + ((k4 ^ (tg & 7)) * 4));
      }
      float4 wv[8];
#pragma unroll
      for (int j = 0; j < 8; j++) {
        int e = eg + 8 * j;
        wv[j] = *(const float4*)(ws + e * 68 + k4 * 4);
      }
#pragma unroll
      for (int i = 0; i < 2; i++)
#pragma unroll
        for (int j = 0; j < 8; j++) {
          acc[i][j] = fmaf(xv[i].x, wv[j].x, acc[i][j]);
          acc[i][j] = fmaf(xv[i].y, wv[j].y, acc[i][j]);
          acc[i][j] = fmaf(xv[i].z, wv[j].z, acc[i][j]);
          acc[i][j] = fmaf(xv[i].w, wv[j].w, acc[i][j]);
        }
    }
    __syncthreads();
  }

  float* outp = Lpart + (size_t)ks * NT * NE;
#pragma unroll
  for (int i = 0; i < 2; i++) {
    const int row = row0 + tg * 2 + i;
#pragma unroll
    for (int j = 0; j < 8; j++)
      outp[(size_t)row * NE + eg + 8 * j] = acc[i][j];
  }
}

// ---------------- K2: reduce slices + bias + center + softmax + gram partial
// 64 tokens/block, 256 blocks. tg=tid>>2 (token), q=tid&3 (16 experts each).
__launch_bounds__(256)
__global__ void k_post(const float* __restrict__ Lpart, const float* __restrict__ b,
                       float* __restrict__ Lg, float* __restrict__ Mg,
                       float* __restrict__ Cpart, int splitk) {
  __shared__ float ms[64 * 68];
  const int tid = threadIdx.x;
  const int tg = tid >> 2, q = tid & 3;
  const int row = blockIdx.x * 64 + tg;

  float l[16];
#pragma unroll
  for (int i = 0; i < 4; i++) {
    float4 bb = *(const float4*)(b + q * 16 + i * 4);
    l[i * 4 + 0] = bb.x; l[i * 4 + 1] = bb.y;
    l[i * 4 + 2] = bb.z; l[i * 4 + 3] = bb.w;
  }
  for (int ks = 0; ks < splitk; ks++) {
    const float* base = Lpart + (size_t)ks * NT * NE + (size_t)row * NE + q * 16;
#pragma unroll
    for (int i = 0; i < 4; i++) {
      float4 v = *(const float4*)(base + i * 4);
      l[i * 4 + 0] += v.x; l[i * 4 + 1] += v.y;
      l[i * 4 + 2] += v.z; l[i * 4 + 3] += v.w;
    }
  }
  float s = 0.f;
#pragma unroll
  for (int j = 0; j < 16; j++) s += l[j];
  s = warp4_sum(s);
  const float mean = s * (1.0f / 64.0f);
  float mx = -1e30f;
#pragma unroll
  for (int j = 0; j < 16; j++) { l[j] -= mean; mx = fmaxf(mx, l[j]); }
  mx = warp4_max(mx);
  float p[16], ps = 0.f;
#pragma unroll
  for (int j = 0; j < 16; j++) { p[j] = expf(l[j] - mx); ps += p[j]; }
  ps = warp4_sum(ps);
  const float inv = 1.0f / ps;
#pragma unroll
  for (int i = 0; i < 4; i++) {
    float4 lv = make_float4(l[i * 4], l[i * 4 + 1], l[i * 4 + 2], l[i * 4 + 3]);
    float4 mv = make_float4(p[i * 4] * inv, p[i * 4 + 1] * inv, p[i * 4 + 2] * inv, p[i * 4 + 3] * inv);
    *(float4*)(Lg + (size_t)row * NE + q * 16 + i * 4) = lv;
    *(float4*)(Mg + (size_t)row * NE + q * 16 + i * 4) = mv;
    *(float4*)(ms + tg * 68 + q * 16 + i * 4) = mv;
  }
  __syncthreads();
  // gram partial: 4x4 per thread over 64 tokens, plain store to Cpart[block]
  const int i0 = (tid >> 4) * 4;
  const int j0 = (tid & 15) * 4;
  float acc[4][4];
#pragma unroll
  for (int a = 0; a < 4; a++)
#pragma unroll
    for (int c = 0; c < 4; c++) acc[a][c] = 0.f;
  for (int t = 0; t < 64; t++) {
    float4 a = *(const float4*)(ms + t * 68 + i0);
    float4 bb = *(const float4*)(ms + t * 68 + j0);
    acc[0][0] = fmaf(a.x, bb.x, acc[0][0]); acc[0][1] = fmaf(a.x, bb.y, acc[0][1]);
    acc[0][2] = fmaf(a.x, bb.z, acc[0][2]); acc[0][3] = fmaf(a.x, bb.w, acc[0][3]);
    acc[1][0] = fmaf(a.y, bb.x, acc[1][0]); acc[1][1] = fmaf(a.y, bb.y, acc[1][1]);
    acc[1][2] = fmaf(a.y, bb.z, acc[1][2]); acc[1][3] = fmaf(a.y, bb.w, acc[1][3]);
    acc[2][0] = fmaf(a.z, bb.x, acc[2][0]); acc[2][1] = fmaf(a.z, bb.y, acc[2][1]);
    acc[2][2] = fmaf(a.z, bb.z, acc[2][2]); acc[2][3] = fmaf(a.z, bb.w, acc[2][3]);
    acc[3][0] = fmaf(a.w, bb.x, acc[3][0]); acc[3][1] = fmaf(a.w, bb.y, acc[3][1]);
    acc[3][2] = fmaf(a.w, bb.z, acc[3][2]); acc[3][3] = fmaf(a.w, bb.w, acc[3][3]);
  }
  float* outp = Cpart + (size_t)blockIdx.x * 4096;
#pragma unroll
  for (int ii = 0; ii < 4; ii++) {
    float4 v = make_float4(acc[ii][0], acc[ii][1], acc[ii][2], acc[ii][3]);
    *(float4*)(outp + (i0 + ii) * 64 + j0) = v;
  }
}

// ---------------- K3: reduce gram partials (fixed order, deterministic) -----
__global__ void k_gram_red(const float* __restrict__ Cpart, float* __restrict__ C) {
  const int idx = blockIdx.x * 256 + threadIdx.x;   // 0..4095
  float s = 0.f;
  for (int bb = 0; bb < 256; bb++) s += Cpart[bb * 4096 + idx];
  C[idx] = s;
}

// ---------------- K4: correction + softmax + first colsum partial -----------
__launch_bounds__(256)
__global__ void k_correct(const float* __restrict__ Lg, float* __restrict__ Mg,
                          const float* __restrict__ C, float* __restrict__ colout) {
  __shared__ float Cs[4096];
  __shared__ float ms[32 * 65];
  __shared__ float cred[4][64];
  const int tid = threadIdx.x;
  const int eg = tid & 7, tg = tid >> 3;
  const int lane = tid & 63, wid = tid >> 6;
  const int row = blockIdx.x * 32 + tg;
#pragma unroll
  for (int i = 0; i < 4; i++) {
    int idx4 = tid + i * 256;
    float4 v = *(const float4*)(C + idx4 * 4);
    int e0 = idx4 * 4;
    int r = e0 >> 6;
    if ((e0 & 63) == r) v.x = 0.f;
    if (((e0 + 1) & 63) == r) v.y = 0.f;
    if (((e0 + 2) & 63) == r) v.z = 0.f;
    if (((e0 + 3) & 63) == r) v.w = 0.f;
    *(float4*)(Cs + e0) = v;
  }
  float m[8];
  {
    float4 a = *(const float4*)(Mg + (size_t)row * NE + eg * 8);
    float4 bb = *(const float4*)(Mg + (size_t)row * NE + eg * 8 + 4);
    m[0] = a.x; m[1] = a.y; m[2] = a.z; m[3] = a.w;
    m[4] = bb.x; m[5] = bb.y; m[6] = bb.z; m[7] = bb.w;
  }
#pragma unroll
  for (int j = 0; j < 8; j++) ms[tg * 65 + eg * 8 + j] = m[j];
  __syncthreads();
  float g[8];
#pragma unroll
  for (int j = 0; j < 8; j++) g[j] = 0.f;
  for (int f = 0; f < 64; f++) {
    float mf = ms[tg * 65 + f];
    float4 c0 = *(const float4*)(Cs + f * 64 + eg * 8);
    float4 c1 = *(const float4*)(Cs + f * 64 + eg * 8 + 4);
    g[0] = fmaf(mf, c0.x, g[0]); g[1] = fmaf(mf, c0.y, g[1]);
    g[2] = fmaf(mf, c0.z, g[2]); g[3] = fmaf(mf, c0.w, g[3]);
    g[4] = fmaf(mf, c1.x, g[4]); g[5] = fmaf(mf, c1.y, g[5]);
    g[6] = fmaf(mf, c1.z, g[6]); g[7] = fmaf(mf, c1.w, g[7]);
  }
  float dot = 0.f;
#pragma unroll
  for (int j = 0; j < 8; j++) dot += m[j] * (4.f * g[j]);
  dot = warp8_sum(dot);
  float l2[8];
  {
    float4 a = *(const float4*)(Lg + (size_t)row * NE + eg * 8);
    float4 bb = *(const float4*)(Lg + (size_t)row * NE + eg * 8 + 4);
    float ll[8] = {a.x, a.y, a.z, a.w, bb.x, bb.y, bb.z, bb.w};
#pragma unroll
    for (int j = 0; j < 8; j++)
      l2[j] = ll[j] - LTAX * (m[j] * (4.f * g[j] - dot));
  }
  float mx = -1e30f;
#pragma unroll
  for (int j = 0; j < 8; j++) mx = fmaxf(mx, l2[j]);
  mx = warp8_max(mx);
  float p[8], ps = 0.f;
#pragma unroll
  for (int j = 0; j < 8; j++) { p[j] = expf(l2[j] - mx); ps += p[j]; }
  ps = warp8_sum(ps);
  const float inv = 1.0f / ps;
  float cs[8];
#pragma unroll
  for (int j = 0; j < 8; j++) { p[j] *= inv; cs[j] = p[j]; }
  float4 o0 = make_float4(p[0], p[1], p[2], p[3]);
  float4 o1 = make_float4(p[4], p[5], p[6], p[7]);
  *(float4*)(Mg + (size_t)row * NE + eg * 8) = o0;
  *(float4*)(Mg + (size_t)row * NE + eg * 8 + 4) = o1;
  // column-sum partial for Sinkhorn iter 1
#pragma unroll
  for (int j = 0; j < 8; j++) {
    cs[j] += __shfl_xor(cs[j], 8);
    cs[j] += __shfl_xor(cs[j], 16);
    cs[j] += __shfl_xor(cs[j], 32);
  }
  if ((lane >> 3) == 0) {
#pragma unroll
    for (int j = 0; j < 8; j++) cred[wid][lane * 8 + j] = cs[j];
  }
  __syncthreads();
  if (tid < 64)
    colout[blockIdx.x * 64 + tid] =
        cred[0][tid] + cred[1][tid] + cred[2][tid] + cred[3][tid];
}

// ---------------- K5: fused Sinkhorn iteration ------------------------------
__launch_bounds__(256)
__global__ void k_sink(float* __restrict__ Mg, const float* __restrict__ colin,
                       int R, float* __restrict__ colout) {
  __shared__ float red[256];
  __shared__ float fac[64];
  __shared__ float cred[4][64];
  const int tid = threadIdx.x;
  const int lane = tid & 63, wid = tid >> 6;
  {
    const int e = tid & 63, q = tid >> 6;
    float s = 0.f;
    for (int r = q; r < R; r += 4) s += colin[r * 64 + e];
    red[tid] = s;
  }
  __syncthreads();
  if (tid < 64) {
    float s = red[tid] + red[tid + 64] + red[tid + 128] + red[tid + 192];
    fac[tid] = (1.0f / 256.0f) / fmaxf(s, 1e-12f);   // (E/n)/clip(colsum)
  }
  __syncthreads();
  const int eg = tid & 7, tg = tid >> 3;
  float f0[8];
#pragma unroll
  for (int j = 0; j < 8; j++) f0[j] = fac[eg * 8 + j];
  float cs[8];
#pragma unroll
  for (int j = 0; j < 8; j++) cs[j] = 0.f;
#pragma unroll
  for (int it = 0; it < 2; it++) {
    const int row = blockIdx.x * 64 + it * 32 + tg;
    float* Mr = Mg + (size_t)row * NE + eg * 8;
    float4 a = *(const float4*)(Mr);
    float4 bb = *(const float4*)(Mr + 4);
    float v[8] = {a.x * f0[0], a.y * f0[1], a.z * f0[2], a.w * f0[3],
                  bb.x * f0[4], bb.y * f0[5], bb.z * f0[6], bb.w * f0[7]};
    float rs = 0.f;
#pragma unroll
    for (int j = 0; j < 8; j++) rs += v[j];
    rs = warp8_sum(rs);
    const float inv = 1.0f / fmaxf(rs, 1e-12f);
#pragma unroll
    for (int j = 0; j < 8; j++) { v[j] *= inv; cs[j] += v[j]; }
    float4 o0 = make_float4(v[0], v[1], v[2], v[3]);
    float4 o1 = make_float4(v[4], v[5], v[6], v[7]);
    *(float4*)(Mr) = o0;
    *(float4*)(Mr + 4) = o1;
  }
#pragma unroll
  for (int j = 0; j < 8; j++) {
    cs[j] += __shfl_xor(cs[j], 8);
    cs[j] += __shfl_xor(cs[j], 16);
    cs[j] += __shfl_xor(cs[j], 32);
  }
  if ((lane >> 3) == 0) {
#pragma unroll
    for (int j = 0; j < 8; j++) cred[wid][lane * 8 + j] = cs[j];
  }
  __syncthreads();
  if (tid < 64)
    colout[blockIdx.x * 64 + tid] =
        cred[0][tid] + cred[1][tid] + cred[2][tid] + cred[3][tid];
}

// ---------------- K6: Sinkhorn iter 10 + damping + hysteresis + topk --------
__launch_bounds__(256)
__global__ void k_final(const float* __restrict__ Mg, const float* __restrict__ colin,
                        const float* __restrict__ pp, const void* __restrict__ pmask,
                        const int* __restrict__ flagp, float* __restrict__ out) {
  __shared__ float red[256];
  __shared__ float fac[64];
  const int tid = threadIdx.x;
  {
    const int e = tid & 63, q = tid >> 6;
    float s = 0.f;
    for (int r = q; r < 256; r += 4) s += colin[r * 64 + e];
    red[tid] = s;
  }
  __syncthreads();
  if (tid < 64) {
    float s = red[tid] + red[tid + 64] + red[tid + 128] + red[tid + 192];
    fac[tid] = (1.0f / 256.0f) / fmaxf(s, 1e-12f);
  }
  __syncthreads();
  const int eg = tid & 7, tg = tid >> 3;
  const int flag = *flagp;
  float f0[8];
#pragma unroll
  for (int j = 0; j < 8; j++) f0[j] = fac[eg * 8 + j];
  float* mout = out;
  float* kout = out + (size_t)NT * NE;
#pragma unroll
  for (int it = 0; it < 2; it++) {
    const int row = blockIdx.x * 64 + it * 32 + tg;
    const float* Mr = Mg + (size_t)row * NE + eg * 8;
    const float* Pr = pp + (size_t)row * NE + eg * 8;
    float4 a = *(const float4*)Mr, b2 = *(const float4*)(Mr + 4);
    float4 c = *(const float4*)Pr, d = *(const float4*)(Pr + 4);
    float mv[8] = {a.x * f0[0], a.y * f0[1], a.z * f0[2], a.w * f0[3],
                   b2.x * f0[4], b2.y * f0[5], b2.z * f0[6], b2.w * f0[7]};
    float rs = 0.f;
#pragma unroll
    for (int j = 0; j < 8; j++) rs += mv[j];
    rs = warp8_sum(rs);
    const float rinv = 1.0f / fmaxf(rs, 1e-12f);
#pragma unroll
    for (int j = 0; j < 8; j++) mv[j] *= rinv;     // Sinkhorn iter 10 done
    float pv[8] = {c.x, c.y, c.z, c.w, d.x, d.y, d.z, d.w};
    float mk[8];
    if (flag == 0) {                 // u8 bytes
      const u32* pb = (const u32*)pmask + row * 16 + eg * 2;
      u32 w0 = pb[0], w1 = pb[1];
#pragma unroll
      for (int j = 0; j < 4; j++) mk[j] = ((w0 >> (8 * j)) & 0xffu) ? 1.f : 0.f;
#pragma unroll
      for (int j = 0; j < 4; j++) mk[4 + j] = ((w1 >> (8 * j)) & 0xffu) ? 1.f : 0.f;
    } else if (flag == 1) {          // int32
      const int* pb = (const int*)pmask + (size_t)row * NE + eg * 8;
#pragma unroll
      for (int j = 0; j < 8; j++) mk[j] = pb[j] ? 1.f : 0.f;
    } else {                         // float32
      const float* pb = (const float*)pmask + (size_t)row * NE + eg * 8;
#pragma unroll
      for (int j = 0; j < 8; j++) mk[j] = (pb[j] != 0.f) ? 1.f : 0.f;
    }
    float msum = 0.f;
#pragma unroll
    for (int j = 0; j < 8; j++) msum += mk[j];
    msum = warp8_sum(msum);
    const float hscale = HYST / fmaxf(msum, 1.0f);
    float v[8];
    float s = 0.f;
#pragma unroll
    for (int j = 0; j < 8; j++) {
      float base = (1.f - ALPHA) * pv[j] + ALPHA * mv[j];
      v[j] = (1.f - HYST) * base + hscale * mk[j];
      s += v[j];
    }
    s = warp8_sum(s);
    const float inv = 1.0f / fmaxf(s, 1e-12f);
#pragma unroll
    for (int j = 0; j < 8; j++) v[j] *= inv;
    {
      float4 o0 = make_float4(v[0], v[1], v[2], v[3]);
      float4 o1 = make_float4(v[4], v[5], v[6], v[7]);
      *(float4*)(mout + (size_t)row * NE + eg * 8) = o0;
      *(float4*)(mout + (size_t)row * NE + eg * 8 + 4) = o1;
    }
    // top-8: expert e selected iff #{f beats e} < 8 (stable descending top_k)
    int cnt[8];
#pragma unroll
    for (int j = 0; j < 8; j++) cnt[j] = 0;
    const int gb = (tid & 63) & ~7;
#pragma unroll
    for (int s8 = 0; s8 < 8; s8++) {
#pragma unroll
      for (int jo = 0; jo < 8; jo++) {
        float o = __shfl(v[jo], gb + s8, 64);
        int oe = s8 * 8 + jo;
#pragma unroll
        for (int j2 = 0; j2 < 8; j2++) {
          int me = eg * 8 + j2;
          if (o > v[j2] || (o == v[j2] && oe < me)) cnt[j2]++;
        }
      }
    }
    float4 k0 = make_float4(cnt[0] < TOPK ? 1.f : 0.f, cnt[1] < TOPK ? 1.f : 0.f,
                            cnt[2] < TOPK ? 1.f : 0.f, cnt[3] < TOPK ? 1.f : 0.f);
    float4 k1 = make_float4(cnt[4] < TOPK ? 1.f : 0.f, cnt[5] < TOPK ? 1.f : 0.f,
                            cnt[6] < TOPK ? 1.f : 0.f, cnt[7] < TOPK ? 1.f : 0.f);
    *(float4*)(kout + (size_t)row * NE + eg * 8) = k0;
    *(float4*)(kout + (size_t)row * NE + eg * 8 + 4) = k1;
  }
}

extern "C" void kernel_launch(void* const* d_in, const int* in_sizes, int n_in,
                              void* d_out, int out_size, void* d_ws, size_t ws_size,
                              hipStream_t stream) {
  const float* x = (const float*)d_in[0];
  const float* W = (const float*)d_in[1];
  const float* b = (const float*)d_in[2];
  const float* pp = (const float*)d_in[3];
  const void* pmask = d_in[4];
  float* out = (float*)d_out;

  // fixed tail footprint (floats): Lbuf + Mbuf + Cpart + Cm + colA + colB + flag
  const size_t tailf = (size_t)NT * NE * 2 + 256 * 4096 + 4096 + 2 * 512 * 64 + 16;
  // pick largest SPLITK whose Lpart fits (ws_size is constant per session ->
  // choice is deterministic across calls)
  int lg = 2;
  while (lg > 0 && (((size_t)NT * NE << lg) + tailf) * sizeof(float) > ws_size) lg--;
  const int splitk = 1 << lg;

  float* wsf = (float*)d_ws;
  float* Lpart = wsf;                                    // splitk * NT*NE
  float* Lbuf = Lpart + ((size_t)NT * NE << lg);         // NT*NE
  float* Mbuf = Lbuf + (size_t)NT * NE;                  // NT*NE
  float* Cpart = Mbuf + (size_t)NT * NE;                 // 256*4096
  float* Cm = Cpart + 256 * 4096;                        // 4096
  float* colA = Cm + 4096;                               // 512*64
  float* colB = colA + 512 * 64;                         // 512*64
  int* flag = (int*)(colB + 512 * 64);

  k_detect<<<1, 256, 0, stream>>>((const uint4*)pmask, flag);
  k_gemm<<<256 << lg, 256, 0, stream>>>(x, W, Lpart, lg);
  k_post<<<256, 256, 0, stream>>>(Lpart, b, Lbuf, Mbuf, Cpart, splitk);
  k_gram_red<<<16, 256, 0, stream>>>(Cpart, Cm);
  k_correct<<<512, 256, 0, stream>>>(Lbuf, Mbuf, Cm, colA);   // colsum #1 (512 rows)
  float* cin = colA; int R = 512; float* cout = colB;
  for (int i = 0; i < 9; i++) {
    k_sink<<<256, 256, 0, stream>>>(Mbuf, cin, R, cout);
    float* t = cin; cin = cout; cout = t;
    R = 256;
  }
  k_final<<<256, 256, 0, stream>>>(Mbuf, cin, pp, pmask, flag, out);
}